// Round 1
// baseline (323.105 us; speedup 1.0000x reference)
//
#include <hip/hip_runtime.h>
#include <hip/hip_bf16.h>

typedef __attribute__((ext_vector_type(8))) short bf16x8;
typedef __attribute__((ext_vector_type(4))) float f32x4;

#define DH 128
#define DOUT 64

static __device__ __forceinline__ unsigned short f2bf(float f) {
    __hip_bfloat16 h = __float2bfloat16(f);
    return *(unsigned short*)&h;
}
static __device__ __forceinline__ void acc2(float& a0, float& a1, unsigned int u) {
    a0 += __uint_as_float(u << 16);
    a1 += __uint_as_float(u & 0xffff0000u);
}

// ---------------- prep: x->bf16, weights->bf16 transposed, zero rows, + histogram ----------------
// cnt[] is zeroed by hipMemsetAsync before this kernel, so the histogram atomics can
// run in the same dispatch as the (independent) conversion work and overlap it.

struct WPrep {
    const float* src[8];
    unsigned short* dst[8];
};

__global__ void prep_kernel(const float* __restrict__ x, unsigned short* __restrict__ xb,
                            unsigned short* __restrict__ hA, unsigned short* __restrict__ hB,
                            int n4, WPrep p,
                            int* __restrict__ cnt, int* __restrict__ rank,
                            const int* __restrict__ dstv, int E, int N_) {
    int id = blockIdx.x * blockDim.x + threadIdx.x;
    if (id < n4) {
        float4 v = ((const float4*)x)[id];
        ushort4 b;
        b.x = f2bf(v.x); b.y = f2bf(v.y); b.z = f2bf(v.z); b.w = f2bf(v.w);
        ((ushort4*)xb)[id] = b;
        return;
    }
    id -= n4;
    if (id < 7 * 16384 + 8192) {
        int m, off;
        if (id < 7 * 16384) { m = id >> 14; off = id & 16383; }
        else { m = 7; off = id - 7 * 16384; }
        int shift = (m == 7) ? 6 : 7;
        int nc = 1 << shift;
        int k = off >> shift;
        int n = off & (nc - 1);
        p.dst[m][n * 128 + k] = f2bf(p.src[m][off]);
        return;
    }
    id -= 7 * 16384 + 8192;
    if (id < 3 * 128) {
        int j = id & 127, w = id >> 7;
        if (w == 0) xb[(size_t)N_ * 128 + j] = 0;
        else if (w == 1) hA[(size_t)N_ * 128 + j] = 0;
        else hB[(size_t)N_ * 128 + j] = 0;
        return;
    }
    id -= 384;
    if (id < E) {
        int d = dstv[id];
        if ((unsigned)d < (unsigned)N_) rank[id] = atomicAdd(&cnt[d], 1);
    }
}

// ---------------- CSR build (degrees padded to multiples of 8; esrc holds byte offsets) ----------------

__global__ void scan1_kernel(const int* __restrict__ cnt, int* __restrict__ rp_part,
                             int* __restrict__ bsum, int n) {
    __shared__ int s[256];
    int tid = threadIdx.x;
    int i = blockIdx.x * 256 + tid;
    int v = (i < n) ? ((cnt[i] + 7) & ~7) : 0;
    s[tid] = v;
    __syncthreads();
    for (int off = 1; off < 256; off <<= 1) {
        int t = (tid >= off) ? s[tid - off] : 0;
        __syncthreads();
        s[tid] += t;
        __syncthreads();
    }
    if (i <= n) rp_part[i] = s[tid] - v;
    if (tid == 255) bsum[blockIdx.x] = s[255];
}

__global__ void scan2_kernel(int* __restrict__ bsum, int nb) {
    __shared__ int s[256];
    int tid = threadIdx.x;
    int v = (tid < nb) ? bsum[tid] : 0;
    s[tid] = v;
    __syncthreads();
    for (int off = 1; off < 256; off <<= 1) {
        int t = (tid >= off) ? s[tid - off] : 0;
        __syncthreads();
        s[tid] += t;
        __syncthreads();
    }
    if (tid < nb) bsum[tid] = s[tid] - v;
}

// Also fills each node's pad tail (<=7 slots) with the zero-row byte offset, replacing
// the old Epad-wide default fill in prep (disjoint slots: scatter writes rank < cnt[d],
// pad fills >= cnt[d] -> no race).
__global__ void scan3_fill_kernel(const int* __restrict__ rp_part, const int* __restrict__ bsum,
                                  int* __restrict__ row_ptr,
                                  const int* __restrict__ src, const int* __restrict__ dst,
                                  const int* __restrict__ rank, const int* __restrict__ cnt,
                                  int* __restrict__ esrc,
                                  int n, int E) {
    int gid = blockIdx.x * blockDim.x + threadIdx.x;
    if (gid <= n) row_ptr[gid] = rp_part[gid] + bsum[gid >> 8];
    if (gid < n) {
        int st = rp_part[gid] + bsum[gid >> 8];
        int c = cnt[gid];
        int pe = (c + 7) & ~7;
        int zr = n << 8;
        for (int j = c; j < pe; ++j) esrc[st + j] = zr;
    }
    if (gid < E) {
        int d = dst[gid];
        if ((unsigned)d < (unsigned)n)
            esrc[rp_part[d] + bsum[d >> 8] + rank[gid]] = src[gid] << 8;  // byte offset
    }
}

// ---------------- fused layer: agg -> GEMM1(relu) -> GEMM2 [-> GEMM3(relu) -> GEMM4] ----------------
// 16-row M tile, 256 threads (4 waves). Gather: block's contiguous CSR edge window staged
// into LDS. Since a wave's 4 nodes are consecutive, their CSR windows form ONE contiguous
// range, and degrees are padded to x8, so every 8-batch lies inside a single node.
// Flat 4-slot (32-load-deep) software pipeline over the whole range — no per-node drain.
// Batch->accumulator routing is a scalar 4-way branch on SGPR boundaries (readfirstlane).

#define ACC8(i, U) \
    _Pragma("unroll") for (int z = 0; z < 8; ++z) acc2(a0[i], a1[i], U[z]);

#define LOAD8(U) \
    if (q < t) { \
        int _o = q - p0; \
        _Pragma("unroll") for (int z = 0; z < 8; ++z) { \
            unsigned _ix = (unsigned)sIdx[_o + z]; \
            U[z] = *(const unsigned*)(hc + _ix + voff); \
        } \
        q += 8; \
    }

#define STEP(U) \
    if (r < t) { \
        int nn = (r >= sE0 ? 1 : 0) + (r >= sE1 ? 1 : 0) + (r >= sE2 ? 1 : 0); \
        if (nn == 0) { ACC8(0, U) } \
        else if (nn == 1) { ACC8(1, U) } \
        else if (nn == 2) { ACC8(2, U) } \
        else { ACC8(3, U) } \
        r += 8; \
        LOAD8(U) \
    }

template <bool HEAD>
__launch_bounds__(256, 7)
__global__ void layer_kernel(const unsigned short* __restrict__ h,
                             const int* __restrict__ rp,
                             const int* __restrict__ esrc,
                             const unsigned short* __restrict__ W1t,
                             const float* __restrict__ b1,
                             const unsigned short* __restrict__ W2t,
                             const float* __restrict__ b2,
                             const unsigned short* __restrict__ W3t,
                             const float* __restrict__ b3,
                             const unsigned short* __restrict__ W4t,
                             const float* __restrict__ b4,
                             void* __restrict__ outp, int M) {
    constexpr int LDA = 128 + 8;
    constexpr int CAP = 2048;
    __shared__ __align__(16) unsigned short As[16][LDA];
    __shared__ __align__(16) unsigned short Zs[16][LDA];
    __shared__ int sIdx[CAP];

    int tid = threadIdx.x;
    int wave = __builtin_amdgcn_readfirstlane(tid >> 6);
    int lane = tid & 63;
    int row0 = blockIdx.x * 16;
    int nd0 = row0 + wave * 4;

    const char* hc = (const char*)h;
    unsigned voff = (unsigned)lane << 2;

    int wbv = rp[row0];
    int Cv = rp[min(row0 + 16, M)] - wbv;
    int wb = __builtin_amdgcn_readfirstlane(wbv);
    int C = __builtin_amdgcn_readfirstlane(Cv);

    // wave's node boundaries (relative to wb), hoisted to SGPRs; all multiples of 8
    int bv[5];
#pragma unroll
    for (int i = 0; i < 5; ++i) bv[i] = rp[min(nd0 + i, M)] - wb;
    int sB  = __builtin_amdgcn_readfirstlane(bv[0]);
    int sE0 = __builtin_amdgcn_readfirstlane(bv[1]);
    int sE1 = __builtin_amdgcn_readfirstlane(bv[2]);
    int sE2 = __builtin_amdgcn_readfirstlane(bv[3]);
    int sE3 = __builtin_amdgcn_readfirstlane(bv[4]);

    float a0[4] = {0.f, 0.f, 0.f, 0.f}, a1[4] = {0.f, 0.f, 0.f, 0.f};

    for (int p0 = 0; p0 < C; p0 += CAP) {
        int cend = min(C, p0 + CAP);
        for (int i = tid; i < cend - p0; i += 256) sIdx[i] = esrc[wb + p0 + i];
        __syncthreads();
        int s = max(sB, p0);
        int t = min(sE3, cend);
        if (s < t) {
            unsigned u0[8], u1[8], u2[8], u3[8];
            int q = s;
            LOAD8(u0) LOAD8(u1) LOAD8(u2) LOAD8(u3)
            int r = s;
            while (r < t) {
                STEP(u0) STEP(u1) STEP(u2) STEP(u3)
            }
        }
        __syncthreads();
    }

    // add self (loaded late to shrink gather-phase live range), pack to LDS
#pragma unroll
    for (int i = 0; i < 4; ++i) {
        int ndc = min(nd0 + i, M);
        unsigned su = *(const unsigned*)(hc + ((size_t)(unsigned)ndc << 8) + voff);
        acc2(a0[i], a1[i], su);
        unsigned pv = (unsigned)f2bf(a0[i]) | ((unsigned)f2bf(a1[i]) << 16);
        *(unsigned*)&As[wave * 4 + i][lane * 2] = pv;
    }
    __syncthreads();

    int quad = lane >> 4;
    int l16 = lane & 15;

    // ---- GEMM1: Zs = relu(As @ W1 + b1) ----
    bf16x8 af[4];
#pragma unroll
    for (int kt = 0; kt < 4; ++kt)
        af[kt] = *(const bf16x8*)(&As[l16][kt * 32 + quad * 8]);
#pragma unroll
    for (int p = 0; p < 2; ++p) {
        int ncol = (wave * 2 + p) * 16 + l16;
        const unsigned short* wp = W1t + ncol * 128 + quad * 8;
        f32x4 a = {0.f, 0.f, 0.f, 0.f};
#pragma unroll
        for (int kt = 0; kt < 4; ++kt)
            a = __builtin_amdgcn_mfma_f32_16x16x32_bf16(
                af[kt], *(const bf16x8*)(wp + kt * 32), a, 0, 0, 0);
        float bs = b1[ncol];
#pragma unroll
        for (int r = 0; r < 4; ++r) {
            float v = a[r] + bs;
            if (v < 0.f) v = 0.f;
            Zs[quad * 4 + r][ncol] = f2bf(v);
        }
    }
    __syncthreads();

    // ---- GEMM2: relu(Zs @ W2 + b2) -> global bf16 (conv) or As (head) ----
    bf16x8 zf[4];
#pragma unroll
    for (int kt = 0; kt < 4; ++kt)
        zf[kt] = *(const bf16x8*)(&Zs[l16][kt * 32 + quad * 8]);
#pragma unroll
    for (int p = 0; p < 2; ++p) {
        int ncol = (wave * 2 + p) * 16 + l16;
        const unsigned short* wp = W2t + ncol * 128 + quad * 8;
        f32x4 a = {0.f, 0.f, 0.f, 0.f};
#pragma unroll
        for (int kt = 0; kt < 4; ++kt)
            a = __builtin_amdgcn_mfma_f32_16x16x32_bf16(
                zf[kt], *(const bf16x8*)(wp + kt * 32), a, 0, 0, 0);
        float bs = b2[ncol];
#pragma unroll
        for (int r = 0; r < 4; ++r) {
            float v = a[r] + bs;
            if (v < 0.f) v = 0.f;
            if (HEAD) {
                As[quad * 4 + r][ncol] = f2bf(v);
            } else {
                int grow = row0 + quad * 4 + r;
                if (grow < M)
                    ((unsigned short*)outp)[(size_t)grow * 128 + ncol] = f2bf(v);
            }
        }
    }

    if (HEAD) {
        __syncthreads();
        // ---- GEMM3: Zs = relu(As @ W3 + b3) ----
        bf16x8 hf[4];
#pragma unroll
        for (int kt = 0; kt < 4; ++kt)
            hf[kt] = *(const bf16x8*)(&As[l16][kt * 32 + quad * 8]);
#pragma unroll
        for (int p = 0; p < 2; ++p) {
            int ncol = (wave * 2 + p) * 16 + l16;
            const unsigned short* wp = W3t + ncol * 128 + quad * 8;
            f32x4 a = {0.f, 0.f, 0.f, 0.f};
#pragma unroll
            for (int kt = 0; kt < 4; ++kt)
                a = __builtin_amdgcn_mfma_f32_16x16x32_bf16(
                    hf[kt], *(const bf16x8*)(wp + kt * 32), a, 0, 0, 0);
            float bs = b3[ncol];
#pragma unroll
            for (int r = 0; r < 4; ++r) {
                float v = a[r] + bs;
                if (v < 0.f) v = 0.f;
                Zs[quad * 4 + r][ncol] = f2bf(v);
            }
        }
        __syncthreads();
        // ---- GEMM4: d_out = Zs @ W4 + b4 (fp32, 64 cols) ----
        bf16x8 gf[4];
#pragma unroll
        for (int kt = 0; kt < 4; ++kt)
            gf[kt] = *(const bf16x8*)(&Zs[l16][kt * 32 + quad * 8]);
        {
            int ncol = wave * 16 + l16;
            const unsigned short* wp = W4t + ncol * 128 + quad * 8;
            f32x4 a = {0.f, 0.f, 0.f, 0.f};
#pragma unroll
            for (int kt = 0; kt < 4; ++kt)
                a = __builtin_amdgcn_mfma_f32_16x16x32_bf16(
                    gf[kt], *(const bf16x8*)(wp + kt * 32), a, 0, 0, 0);
            float bs = b4[ncol];
#pragma unroll
            for (int r = 0; r < 4; ++r) {
                int grow = row0 + quad * 4 + r;
                if (grow < M)
                    ((float*)outp)[(size_t)grow * 64 + ncol] = a[r] + bs;
            }
        }
    }
}

// ---------------- launch ----------------

extern "C" void kernel_launch(void* const* d_in, const int* in_sizes, int n_in,
                              void* d_out, int out_size, void* d_ws, size_t ws_size,
                              hipStream_t stream) {
    const float* x = (const float*)d_in[0];
    const int* ei = (const int*)d_in[1];
    int N = in_sizes[0] / DH;
    int E = in_sizes[1] / 2;
    const int* src = ei;
    const int* dstv = ei + E;
    int Epad = E + 7 * N + 1024;  // worst-case padded edge count + slack

    char* ws = (char*)d_ws;
    size_t off = 0;
    auto alloc = [&](size_t bytes) -> void* {
        void* p = ws + off;
        off += (bytes + 255) & ~(size_t)255;
        return p;
    };
    // feature buffers have N+1 rows; row N is the zero row
    unsigned short* xb = (unsigned short*)alloc((size_t)(N + 1) * DH * 2);
    unsigned short* hA = (unsigned short*)alloc((size_t)(N + 1) * DH * 2);
    unsigned short* hB = (unsigned short*)alloc((size_t)(N + 1) * DH * 2);
    unsigned short* wt[8];
    for (int m = 0; m < 8; ++m) wt[m] = (unsigned short*)alloc(16384 * 2);
    int* cnt     = (int*)alloc((size_t)N * 4);
    int* rp_part = (int*)alloc((size_t)(N + 1) * 4);
    int* row_ptr = (int*)alloc((size_t)(N + 1) * 4);
    int* rank    = (int*)alloc((size_t)E * 4);
    int* bsum    = (int*)alloc(256 * 4);
    int* esrc    = (int*)alloc((size_t)Epad * 4);

    WPrep wp;
    wp.src[0] = (const float*)d_in[2];
    wp.src[1] = (const float*)d_in[4];
    wp.src[2] = (const float*)d_in[6];
    wp.src[3] = (const float*)d_in[8];
    wp.src[4] = (const float*)d_in[10];
    wp.src[5] = (const float*)d_in[12];
    wp.src[6] = (const float*)d_in[14];
    wp.src[7] = (const float*)d_in[16];
    for (int m = 0; m < 8; ++m) wp.dst[m] = wt[m];

    // zero the degree counters, then one kernel does conversion work + histogram
    hipMemsetAsync(cnt, 0, (size_t)N * 4, stream);

    int n4 = N * DH / 4;
    int prep_items = n4 + 7 * 16384 + 8192 + 384 + E;
    prep_kernel<<<(prep_items + 255) / 256, 256, 0, stream>>>(
        x, xb, hA, hB, n4, wp, cnt, rank, dstv, E, N);

    int nb = (N + 1 + 255) / 256;
    int eb = (E + 255) / 256;
    scan1_kernel<<<nb, 256, 0, stream>>>(cnt, rp_part, bsum, N);
    scan2_kernel<<<1, 256, 0, stream>>>(bsum, nb);
    scan3_fill_kernel<<<eb, 256, 0, stream>>>(rp_part, bsum, row_ptr,
                                              src, dstv, rank, cnt, esrc, N, E);

    int gb = (N + 15) / 16;

    const float* c1b1 = (const float*)d_in[3];
    const float* c1b2 = (const float*)d_in[5];
    const float* c2b1 = (const float*)d_in[7];
    const float* c2b2 = (const float*)d_in[9];
    const float* c3b1 = (const float*)d_in[11];
    const float* c3b2 = (const float*)d_in[13];
    const float* l1b  = (const float*)d_in[15];
    const float* l2b  = (const float*)d_in[17];

    layer_kernel<false><<<gb, 256, 0, stream>>>(
        xb, row_ptr, esrc, wt[0], c1b1, wt[1], c1b2,
        nullptr, nullptr, nullptr, nullptr, hA, N);
    layer_kernel<false><<<gb, 256, 0, stream>>>(
        hA, row_ptr, esrc, wt[2], c2b1, wt[3], c2b2,
        nullptr, nullptr, nullptr, nullptr, hB, N);
    layer_kernel<true><<<gb, 256, 0, stream>>>(
        hB, row_ptr, esrc, wt[4], c3b1, wt[5], c3b2,
        wt[6], l1b, wt[7], l2b, d_out, N);
}